// Round 2
// baseline (1886.955 us; speedup 1.0000x reference)
//
#include <hip/hip_runtime.h>

#define S_TOK 8192
#define DIM   1024
#define DIM2  2048
#define OUTN  1024

typedef __bf16 bf16x8 __attribute__((ext_vector_type(8)));
typedef float  f32x4  __attribute__((ext_vector_type(4)));
typedef short  s16x8  __attribute__((ext_vector_type(8)));
typedef unsigned short u16x4 __attribute__((ext_vector_type(4)));

__device__ __forceinline__ unsigned short f2bf(float x) {
  unsigned u = __builtin_bit_cast(unsigned, x);
  u = (u + 0x7FFFu + ((u >> 16) & 1u)) >> 16;
  return (unsigned short)u;
}
__device__ __forceinline__ float bf2f(unsigned short u) {
  return __builtin_bit_cast(float, (unsigned)u << 16);
}

// async global->LDS, 16B per lane. LDS dest must be wave-uniform base;
// HW writes base + lane*16. Global src is per-lane (gather).
__device__ __forceinline__ void gld_lds16(const void* g, void* l) {
  auto* g1 = reinterpret_cast<__attribute__((address_space(1))) unsigned*>(
      (unsigned long long)g);
  auto* l3 = reinterpret_cast<__attribute__((address_space(3))) unsigned*>(
      (unsigned long long)l);
  __builtin_amdgcn_global_load_lds(g1, l3, 16, 0, 0);
}

// Swizzled LDS byte offset for a [128][64] bf16 tile (idx-major, k inner).
// XOR bits [6:4] with (idx ^ idx>>3)&7. Staging writes are LINEAR (slot c*16);
// the swizzle is realized by pre-XORing the GLOBAL source k-chunk (m173 pattern).
__device__ __forceinline__ int lds_off(int idx, int k) {
  int b = (idx << 7) + (k << 1);
  b ^= ((idx ^ (idx >> 3)) & 7) << 4;
  return b;
}

__global__ __launch_bounds__(256) void cvt_f32_bf16(const float* __restrict__ in,
                                                    unsigned short* __restrict__ out, int n4) {
  int i = blockIdx.x * 256 + threadIdx.x;
  if (i >= n4) return;
  float4 v = ((const float4*)in)[i];
  u16x4 o;
  o[0] = f2bf(v.x); o[1] = f2bf(v.y); o[2] = f2bf(v.z); o[3] = f2bf(v.w);
  *(u16x4*)(out + (size_t)i * 4) = o;
}

// Tiled transpose: in [R,C] (f32 or bf16) -> out [C,R] bf16. 64x64 tiles, 256 thr.
// LDS tile swizzled so both phases are <=2-way bank-conflicted.
template <int F32IN>
__global__ __launch_bounds__(256) void transpose_to_bf16(const void* __restrict__ in,
                                                         unsigned short* __restrict__ out,
                                                         int R, int C) {
  __shared__ unsigned short t[64 * 64];
  const int r0 = blockIdx.y << 6, c0 = blockIdx.x << 6;
  const int tid = threadIdx.x;
#pragma unroll
  for (int i = 0; i < 2; ++i) {
    int ch = tid + (i << 8);
    int r = ch >> 3, c8 = (ch & 7) << 3;
    s16x8 w;
    if (F32IN) {
      const float* p = (const float*)in + (size_t)(r0 + r) * C + c0 + c8;
      float4 a = *(const float4*)p, b = *(const float4*)(p + 4);
      w[0] = (short)f2bf(a.x); w[1] = (short)f2bf(a.y);
      w[2] = (short)f2bf(a.z); w[3] = (short)f2bf(a.w);
      w[4] = (short)f2bf(b.x); w[5] = (short)f2bf(b.y);
      w[6] = (short)f2bf(b.z); w[7] = (short)f2bf(b.w);
    } else {
      w = *(const s16x8*)((const unsigned short*)in + (size_t)(r0 + r) * C + c0 + c8);
    }
    int sw = ((r ^ (r >> 3)) & 7) << 3;
    *(s16x8*)&t[(r << 6) + (c8 ^ sw)] = w;
  }
  __syncthreads();
#pragma unroll
  for (int i = 0; i < 2; ++i) {
    int ch = tid + (i << 8);
    int c = ch >> 3, r8 = (ch & 7) << 3;
    s16x8 w;
#pragma unroll
    for (int j = 0; j < 8; ++j) {
      int rr = r8 + j;
      w[j] = (short)t[(rr << 6) + (c ^ (((rr ^ (rr >> 3)) & 7) << 3))];
    }
    *(s16x8*)(out + (size_t)(c0 + c) * R + r0 + r8) = w;
  }
}

// Softmax over the ROW axis (2048 features) of T [2048, S_TOK], per column, in place.
// Block 512 thr = 64 cols x 8 segments; fully-coalesced 128B lines per wave.
__global__ __launch_bounds__(512) void softmax_cols(unsigned short* __restrict__ T) {
  const int tid = threadIdx.x;
  const int colg = tid & 63, seg = tid >> 6;
  const size_t c = ((size_t)blockIdx.x << 6) + colg;
  __shared__ float redm[512], reds[512];
  float m = -1e30f;
  for (int n = seg; n < DIM2; n += 8)
    m = fmaxf(m, bf2f(T[(size_t)n * S_TOK + c]));
  redm[tid] = m;
  __syncthreads();
  if (seg == 0) {
#pragma unroll
    for (int k = 1; k < 8; ++k) m = fmaxf(m, redm[colg + (k << 6)]);
    redm[colg] = m;
  }
  __syncthreads();
  m = redm[colg];
  float s = 0.f;
  for (int n = seg; n < DIM2; n += 8)
    s += __expf(bf2f(T[(size_t)n * S_TOK + c]) - m);
  reds[tid] = s;
  __syncthreads();
  if (seg == 0) {
#pragma unroll
    for (int k = 1; k < 8; ++k) s += reds[colg + (k << 6)];
    reds[colg] = 1.0f / s;
  }
  __syncthreads();
  const float inv = reds[colg];
  for (int n = seg; n < DIM2; n += 8) {
    size_t idx = (size_t)n * S_TOK + c;
    T[idx] = f2bf(__expf(bf2f(T[idx]) - m) * inv);
  }
}

// GEMM: C[M,N] = epi(A @ B^T * scale + bias), A [M,K] row-major, B [N,K] row-major.
// BSPLIT: B row n reads from B for k<DIM, B2 at k-DIM otherwise (virtual concat),
//         both with row stride ldb (=DIM).
// Tile 128x128, BK=64, 4 waves. Staging via global_load_lds width 16 (linear LDS,
// pre-swizzled global source); fragment reads via swizzled lds_off.
template <int BSPLIT, int BIAS_ROW, int OUT_BF16>
__global__ __launch_bounds__(256, 2) void gemm_nt(
    const unsigned short* __restrict__ A, int lda,
    const unsigned short* __restrict__ B, const unsigned short* __restrict__ B2, int ldb,
    const float* __restrict__ bias, void* __restrict__ Cv, int ldc,
    int K, float scale, int do_relu) {
  __shared__ char lds[32768];
  char* As = lds;
  char* Bs = lds + 16384;
  const int tid  = threadIdx.x;
  const int lane = tid & 63;
  const int wave = tid >> 6;
  const int wm = (wave >> 1) << 6;
  const int wn = (wave & 1) << 6;
  const int m0 = blockIdx.y << 7;
  const int n0 = blockIdx.x << 7;

  // staging geometry: chunk c = wave*256 + i*64 + lane -> (row, k-chunk),
  // source k pre-XORed so the linear LDS write realizes the swizzle.
  int srow[4], sgk[4];
#pragma unroll
  for (int i = 0; i < 4; ++i) {
    int c = (wave << 8) + (i << 6) + lane;
    int row = c >> 3, kc = c & 7;
    srow[i] = row;
    sgk[i]  = (kc ^ ((row ^ (row >> 3)) & 7)) << 3;
  }

  f32x4 acc[4][4];
#pragma unroll
  for (int i = 0; i < 4; ++i)
#pragma unroll
    for (int j = 0; j < 4; ++j) acc[i][j] = {0.f, 0.f, 0.f, 0.f};

  for (int k0 = 0; k0 < K; k0 += 64) {
    const unsigned short* bsrc = B;
    int kb = k0;
    if (BSPLIT && k0 >= DIM) { bsrc = B2; kb = k0 - DIM; }
#pragma unroll
    for (int i = 0; i < 4; ++i) {
      char* dA = As + ((((wave << 2) + i)) << 10);
      char* dB = Bs + ((((wave << 2) + i)) << 10);
      gld_lds16(A    + (size_t)(m0 + srow[i]) * lda + k0 + sgk[i], dA);
      gld_lds16(bsrc + (size_t)(n0 + srow[i]) * ldb + kb + sgk[i], dB);
    }
    __syncthreads();  // drains vmcnt -> LDS tiles complete
#pragma unroll
    for (int ks = 0; ks < 2; ++ks) {
      bf16x8 af[4], bfr[4];
      int kk = (ks << 5) + ((lane >> 4) << 3);
#pragma unroll
      for (int t = 0; t < 4; ++t) {
        af[t]  = *(const bf16x8*)(As + lds_off(wm + (t << 4) + (lane & 15), kk));
        bfr[t] = *(const bf16x8*)(Bs + lds_off(wn + (t << 4) + (lane & 15), kk));
      }
#pragma unroll
      for (int mt = 0; mt < 4; ++mt)
#pragma unroll
        for (int nt = 0; nt < 4; ++nt)
          acc[mt][nt] = __builtin_amdgcn_mfma_f32_16x16x32_bf16(af[mt], bfr[nt], acc[mt][nt], 0, 0, 0);
    }
    __syncthreads();
  }

  // epilogue: C/D layout col = lane&15, row = (lane>>4)*4 + r
#pragma unroll
  for (int nt = 0; nt < 4; ++nt) {
    int col = n0 + wn + (nt << 4) + (lane & 15);
    float bcol = (!BIAS_ROW && bias) ? bias[col] : 0.0f;
#pragma unroll
    for (int mt = 0; mt < 4; ++mt) {
      f32x4 a = acc[mt][nt];
#pragma unroll
      for (int r = 0; r < 4; ++r) {
        int rowg = m0 + wm + (mt << 4) + ((lane >> 4) << 2) + r;
        float bv = BIAS_ROW ? (bias ? bias[rowg] : 0.0f) : bcol;
        float v = a[r] * scale + bv;
        if (do_relu) v = fmaxf(v, 0.0f);
        if (OUT_BF16) ((unsigned short*)Cv)[(size_t)rowg * ldc + col] = f2bf(v);
        else          ((float*)Cv)[(size_t)rowg * ldc + col] = v;
      }
    }
  }
}

extern "C" void kernel_launch(void* const* d_in, const int* in_sizes, int n_in,
                              void* d_out, int out_size, void* d_ws, size_t ws_size,
                              hipStream_t stream) {
  const float* X   = (const float*)d_in[0];
  const float* Y   = (const float*)d_in[1];
  const float* R   = (const float*)d_in[2];
  const float* Wi  = (const float*)d_in[3];
  const float* bi  = (const float*)d_in[4];
  const float* Wo  = (const float*)d_in[5];
  const float* bo  = (const float*)d_in[6];
  const float* Wc  = (const float*)d_in[7];
  const float* bc  = (const float*)d_in[8];
  const float* Wf  = (const float*)d_in[9];
  const float* bf_ = (const float*)d_in[10];
  float* out = (float*)d_out;

  char* ws = (char*)d_ws;
  size_t off = 0;
  auto alloc = [&](size_t b) { char* p = ws + off; off += (b + 255) & ~(size_t)255; return p; };
  unsigned short* Xb   = (unsigned short*)alloc((size_t)S_TOK * DIM  * 2);  // 16MB
  unsigned short* Yb   = (unsigned short*)alloc((size_t)S_TOK * DIM  * 2);  // 16MB (R reuses)
  unsigned short* WiT  = (unsigned short*)alloc((size_t)DIM2 * DIM  * 2);   // 4MB  [2048,1024]
  unsigned short* WoT  = (unsigned short*)alloc((size_t)DIM2 * DIM  * 2);   // 4MB
  unsigned short* WcT  = (unsigned short*)alloc((size_t)DIM2 * DIM2 * 2);   // 8MB  [2048,2048]
  unsigned short* WfT  = (unsigned short*)alloc((size_t)OUTN * DIM2 * 2);   // 4MB  [1024,2048]
  unsigned short* iqT  = (unsigned short*)alloc((size_t)DIM2 * S_TOK * 2);  // 32MB [2048,8192]
  unsigned short* oqT  = (unsigned short*)alloc((size_t)DIM2 * S_TOK * 2);  // 32MB
  unsigned short* icmT = (unsigned short*)alloc((size_t)DIM2 * S_TOK * 2);  // 32MB (res aliases)
  unsigned short* icm  = (unsigned short*)alloc((size_t)S_TOK * DIM2 * 2);  // 32MB [8192,2048]
  unsigned short* iqk  = (unsigned short*)alloc((size_t)DIM2 * DIM2 * 2);   // 8MB
  unsigned short* oqk  = (unsigned short*)alloc((size_t)DIM2 * DIM2 * 2);   // 8MB
  unsigned short* metaT= (unsigned short*)alloc((size_t)DIM2 * DIM2 * 2);   // 8MB
  unsigned short* res  = icmT;  // icmT dead once oqk is done; res written after

  auto cvt = [&](const float* s, unsigned short* d, int n) {
    int n4 = n >> 2;
    cvt_f32_bf16<<<dim3((n4 + 255) / 256), dim3(256), 0, stream>>>(s, d, n4);
  };
  cvt(X, Xb, S_TOK * DIM);
  cvt(Y, Yb, S_TOK * DIM);
  // weight transposes (f32 -> bf16, [R,C] -> [C,R])
  transpose_to_bf16<1><<<dim3(DIM2 / 64, DIM  / 64), 256, 0, stream>>>(Wi, WiT, DIM,  DIM2);
  transpose_to_bf16<1><<<dim3(DIM2 / 64, DIM  / 64), 256, 0, stream>>>(Wo, WoT, DIM,  DIM2);
  transpose_to_bf16<1><<<dim3(DIM2 / 64, DIM2 / 64), 256, 0, stream>>>(Wc, WcT, DIM2, DIM2);
  transpose_to_bf16<1><<<dim3(OUTN / 64, DIM2 / 64), 256, 0, stream>>>(Wf, WfT, DIM2, OUTN);

  const float rscale = 0.022097086912079608f;  // 1/sqrt(2048)

  // iqT = colsoftmax( (X@Wi + bi)^T ) = colsoftmax( gemm(WiT, X-as-[N,K]) ) -- shared
  gemm_nt<0, 1, 1><<<dim3(S_TOK / 128, DIM2 / 128), 256, 0, stream>>>(
      WiT, DIM, Xb, nullptr, DIM, bi, iqT, S_TOK, DIM, 1.f, 0);
  softmax_cols<<<dim3(S_TOK / 64), dim3(512), 0, stream>>>(iqT);

  for (int pass = 0; pass < 2; ++pass) {
    if (pass == 1) cvt(R, Yb, S_TOK * DIM);  // Yb now holds random_augmentation
    float* outp = out + (size_t)pass * S_TOK * OUTN;

    // oqT = colsoftmax( (y@Wo + bo)^T )
    gemm_nt<0, 1, 1><<<dim3(S_TOK / 128, DIM2 / 128), 256, 0, stream>>>(
        WoT, DIM, Yb, nullptr, DIM, bo, oqT, S_TOK, DIM, 1.f, 0);
    softmax_cols<<<dim3(S_TOK / 64), dim3(512), 0, stream>>>(oqT);

    // icmT = colsoftmax( (cat@Wc + bc)^T ), concat on the B-side K-split
    gemm_nt<1, 1, 1><<<dim3(S_TOK / 128, DIM2 / 128), 256, 0, stream>>>(
        WcT, DIM2, Xb, Yb, DIM, bc, icmT, S_TOK, DIM2, 1.f, 0);
    softmax_cols<<<dim3(S_TOK / 64), dim3(512), 0, stream>>>(icmT);

    // icm = transpose(icmT)  [8192, 2048] -- needed as the A operand of res
    transpose_to_bf16<0><<<dim3(S_TOK / 64, DIM2 / 64), 256, 0, stream>>>(
        icmT, icm, DIM2, S_TOK);

    // iqk = iq^T @ icm = iqT @ icmT^T ; oqk likewise   [2048,2048], K=8192
    gemm_nt<0, 0, 1><<<dim3(DIM2 / 128, DIM2 / 128), 256, 0, stream>>>(
        iqT, S_TOK, icmT, nullptr, S_TOK, nullptr, iqk, DIM2, S_TOK, 1.f, 0);
    gemm_nt<0, 0, 1><<<dim3(DIM2 / 128, DIM2 / 128), 256, 0, stream>>>(
        oqT, S_TOK, icmT, nullptr, S_TOK, nullptr, oqk, DIM2, S_TOK, 1.f, 0);

    // metaT = relu(oqk @ iqk^T)   (= meta^T, free transposed output)
    gemm_nt<0, 0, 1><<<dim3(DIM2 / 128, DIM2 / 128), 256, 0, stream>>>(
        oqk, DIM2, iqk, nullptr, DIM2, nullptr, metaT, DIM2, DIM2, 1.f, 1);

    // res = (icm @ meta) / sqrt(2048) = icm @ metaT^T   [8192,2048]
    gemm_nt<0, 0, 1><<<dim3(DIM2 / 128, S_TOK / 128), 256, 0, stream>>>(
        icm, DIM2, metaT, nullptr, DIM2, nullptr, res, DIM2, DIM2, rscale, 0);

    // out = relu(res @ Wf + bf) = relu(res @ WfT^T + bf)   [8192,1024] f32
    gemm_nt<0, 0, 0><<<dim3(OUTN / 128, S_TOK / 128), 256, 0, stream>>>(
        res, DIM2, WfT, nullptr, DIM2, bf_, outp, OUTN, DIM2, 1.f, 1);
  }
  (void)in_sizes; (void)n_in; (void)out_size; (void)ws_size;
}

// Round 3
// 993.735 us; speedup vs baseline: 1.8989x; 1.8989x over previous
//
#include <hip/hip_runtime.h>

#define S_TOK 8192
#define DIM   1024
#define DIM2  2048
#define OUTN  1024

typedef __bf16 bf16x8 __attribute__((ext_vector_type(8)));
typedef float  f32x4  __attribute__((ext_vector_type(4)));
typedef short  s16x8  __attribute__((ext_vector_type(8)));
typedef unsigned short u16x4 __attribute__((ext_vector_type(4)));

__device__ __forceinline__ unsigned short f2bf(float x) {
  unsigned u = __builtin_bit_cast(unsigned, x);
  u = (u + 0x7FFFu + ((u >> 16) & 1u)) >> 16;
  return (unsigned short)u;
}
__device__ __forceinline__ float bf2f(unsigned short u) {
  return __builtin_bit_cast(float, (unsigned)u << 16);
}

__device__ __forceinline__ void gld_lds16(const void* g, void* l) {
  auto* g1 = reinterpret_cast<__attribute__((address_space(1))) unsigned*>(
      (unsigned long long)g);
  auto* l3 = reinterpret_cast<__attribute__((address_space(3))) unsigned*>(
      (unsigned long long)l);
  __builtin_amdgcn_global_load_lds(g1, l3, 16, 0, 0);
}

// Swizzled LDS byte offset for a [128][64] bf16 tile (idx-major, k inner).
__device__ __forceinline__ int lds_off(int idx, int k) {
  int b = (idx << 7) + (k << 1);
  b ^= ((idx ^ (idx >> 3)) & 7) << 4;
  return b;
}

__global__ __launch_bounds__(256) void cvt_f32_bf16(const float* __restrict__ in,
                                                    unsigned short* __restrict__ out, int n4) {
  int i = blockIdx.x * 256 + threadIdx.x;
  if (i >= n4) return;
  float4 v = ((const float4*)in)[i];
  u16x4 o;
  o[0] = f2bf(v.x); o[1] = f2bf(v.y); o[2] = f2bf(v.z); o[3] = f2bf(v.w);
  *(u16x4*)(out + (size_t)i * 4) = o;
}

// Tiled transpose: in [R,C] (f32 or bf16) -> out [C,R] bf16. 64x64 tiles, 256 thr.
template <int F32IN>
__global__ __launch_bounds__(256) void transpose_to_bf16(const void* __restrict__ in,
                                                         unsigned short* __restrict__ out,
                                                         int R, int C) {
  __shared__ unsigned short t[64 * 64];
  const int r0 = blockIdx.y << 6, c0 = blockIdx.x << 6;
  const int tid = threadIdx.x;
#pragma unroll
  for (int i = 0; i < 2; ++i) {
    int ch = tid + (i << 8);
    int r = ch >> 3, c8 = (ch & 7) << 3;
    s16x8 w;
    if (F32IN) {
      const float* p = (const float*)in + (size_t)(r0 + r) * C + c0 + c8;
      float4 a = *(const float4*)p, b = *(const float4*)(p + 4);
      w[0] = (short)f2bf(a.x); w[1] = (short)f2bf(a.y);
      w[2] = (short)f2bf(a.z); w[3] = (short)f2bf(a.w);
      w[4] = (short)f2bf(b.x); w[5] = (short)f2bf(b.y);
      w[6] = (short)f2bf(b.z); w[7] = (short)f2bf(b.w);
    } else {
      w = *(const s16x8*)((const unsigned short*)in + (size_t)(r0 + r) * C + c0 + c8);
    }
    int sw = ((r ^ (r >> 3)) & 7) << 3;
    *(s16x8*)&t[(r << 6) + (c8 ^ sw)] = w;
  }
  __syncthreads();
#pragma unroll
  for (int i = 0; i < 2; ++i) {
    int ch = tid + (i << 8);
    int c = ch >> 3, r8 = (ch & 7) << 3;
    s16x8 w;
#pragma unroll
    for (int j = 0; j < 8; ++j) {
      int rr = r8 + j;
      w[j] = (short)t[(rr << 6) + (c ^ (((rr ^ (rr >> 3)) & 7) << 3))];
    }
    *(s16x8*)(out + (size_t)(c0 + c) * R + r0 + r8) = w;
  }
}

// Softmax over the ROW axis (2048 feats) of T [2048, S_TOK], per column, in place.
// blockIdx.y selects one of up to 6 buffers; online max+sum (2 passes over data).
struct SmTab { unsigned short* T[6]; };
__global__ __launch_bounds__(512) void softmax_cols(SmTab tab) {
  unsigned short* T = tab.T[blockIdx.y];
  const int tid = threadIdx.x;
  const int colg = tid & 63, seg = tid >> 6;
  const size_t c = ((size_t)blockIdx.x << 6) + colg;
  float m = -1e30f, s = 0.f;
  for (int n = seg; n < DIM2; n += 8) {
    float v = bf2f(T[(size_t)n * S_TOK + c]);
    float mn = fmaxf(m, v);
    s = s * __expf(m - mn) + __expf(v - mn);
    m = mn;
  }
  __shared__ float redm[512], reds[512];
  redm[tid] = m; reds[tid] = s;
  __syncthreads();
  if (seg == 0) {
    float M = m, S = s;
#pragma unroll
    for (int k = 1; k < 8; ++k) {
      float mk = redm[colg + (k << 6)], sk = reds[colg + (k << 6)];
      float mn = fmaxf(M, mk);
      S = S * __expf(M - mn) + sk * __expf(mk - mn);
      M = mn;
    }
    redm[colg] = M; reds[colg] = 1.0f / S;
  }
  __syncthreads();
  m = redm[colg];
  const float inv = reds[colg];
  for (int n = seg; n < DIM2; n += 8) {
    size_t idx = (size_t)n * S_TOK + c;
    T[idx] = f2bf(__expf(bf2f(T[idx]) - m) * inv);
  }
}

// Grouped GEMM: for z = blockIdx.z, C_z[M,N] = epi(A_z @ B_z^T * scale + bias_z).
// A [M,K] rm, B [N,K] rm. ASPLIT: A rows >= 2048 come from Arow2[z] (row-2048).
// BSPLIT: B cols k >= DIM come from Bk2[z] (k-DIM), both row-stride ldb.
// Tile 128x128, BK=64, 4 waves; global_load_lds w16, pre-swizzled source.
struct GPtr {
  const unsigned short* A[3];
  const unsigned short* Arow2[3];
  const unsigned short* B[3];
  const unsigned short* Bk2[3];
  const float* bias[3];
  void* C[3];
};
template <int ASPLIT, int BSPLIT, int BIAS_ROW, int OUT_BF16>
__global__ __launch_bounds__(256, 3) void gemm_nt(GPtr p, int lda, int ldb, int ldc,
                                                  int K, float scale, int do_relu) {
  __shared__ char lds[32768];
  char* As = lds;
  char* Bs = lds + 16384;
  const int z = blockIdx.z;
  const int tid  = threadIdx.x;
  const int lane = tid & 63;
  const int wave = tid >> 6;
  const int wm = (wave >> 1) << 6;
  const int wn = (wave & 1) << 6;
  const int m0 = blockIdx.y << 7;
  const int n0 = blockIdx.x << 7;

  const unsigned short* Au = p.A[z];
  int mb = m0;
  if (ASPLIT && m0 >= 2048) { Au = p.Arow2[z]; mb = m0 - 2048; }
  const unsigned short* B  = p.B[z];
  const unsigned short* B2 = BSPLIT ? p.Bk2[z] : B;
  const float* bias = p.bias[z];
  void* Cv = p.C[z];

  int srow[4], sgk[4];
#pragma unroll
  for (int i = 0; i < 4; ++i) {
    int c = (wave << 8) + (i << 6) + lane;
    int row = c >> 3, kc = c & 7;
    srow[i] = row;
    sgk[i]  = (kc ^ ((row ^ (row >> 3)) & 7)) << 3;
  }

  f32x4 acc[4][4];
#pragma unroll
  for (int i = 0; i < 4; ++i)
#pragma unroll
    for (int j = 0; j < 4; ++j) acc[i][j] = {0.f, 0.f, 0.f, 0.f};

  for (int k0 = 0; k0 < K; k0 += 64) {
    const unsigned short* bsrc = B;
    int kb = k0;
    if (BSPLIT && k0 >= DIM) { bsrc = B2; kb = k0 - DIM; }
#pragma unroll
    for (int i = 0; i < 4; ++i) {
      char* dA = As + (((wave << 2) + i) << 10);
      char* dB = Bs + (((wave << 2) + i) << 10);
      gld_lds16(Au   + (size_t)(mb + srow[i]) * lda + k0 + sgk[i], dA);
      gld_lds16(bsrc + (size_t)(n0 + srow[i]) * ldb + kb + sgk[i], dB);
    }
    __syncthreads();
#pragma unroll
    for (int ks = 0; ks < 2; ++ks) {
      bf16x8 af[4], bfr[4];
      int kk = (ks << 5) + ((lane >> 4) << 3);
#pragma unroll
      for (int t = 0; t < 4; ++t) {
        af[t]  = *(const bf16x8*)(As + lds_off(wm + (t << 4) + (lane & 15), kk));
        bfr[t] = *(const bf16x8*)(Bs + lds_off(wn + (t << 4) + (lane & 15), kk));
      }
#pragma unroll
      for (int mt = 0; mt < 4; ++mt)
#pragma unroll
        for (int nt = 0; nt < 4; ++nt)
          acc[mt][nt] = __builtin_amdgcn_mfma_f32_16x16x32_bf16(af[mt], bfr[nt], acc[mt][nt], 0, 0, 0);
    }
    __syncthreads();
  }

#pragma unroll
  for (int nt = 0; nt < 4; ++nt) {
    int col = n0 + wn + (nt << 4) + (lane & 15);
    float bcol = (!BIAS_ROW && bias) ? bias[col] : 0.0f;
#pragma unroll
    for (int mt = 0; mt < 4; ++mt) {
      f32x4 a = acc[mt][nt];
#pragma unroll
      for (int r = 0; r < 4; ++r) {
        int rowg = m0 + wm + (mt << 4) + ((lane >> 4) << 2) + r;
        float bv = BIAS_ROW ? (bias ? bias[rowg] : 0.0f) : bcol;
        float v = a[r] * scale + bv;
        if (do_relu) v = fmaxf(v, 0.0f);
        if (OUT_BF16) ((unsigned short*)Cv)[(size_t)rowg * ldc + col] = f2bf(v);
        else          ((float*)Cv)[(size_t)rowg * ldc + col] = v;
      }
    }
  }
}

extern "C" void kernel_launch(void* const* d_in, const int* in_sizes, int n_in,
                              void* d_out, int out_size, void* d_ws, size_t ws_size,
                              hipStream_t stream) {
  const float* X   = (const float*)d_in[0];
  const float* Y   = (const float*)d_in[1];
  const float* R   = (const float*)d_in[2];
  const float* Wi  = (const float*)d_in[3];
  const float* bi  = (const float*)d_in[4];
  const float* Wo  = (const float*)d_in[5];
  const float* bo  = (const float*)d_in[6];
  const float* Wc  = (const float*)d_in[7];
  const float* bc  = (const float*)d_in[8];
  const float* Wf  = (const float*)d_in[9];
  const float* bf_ = (const float*)d_in[10];
  float* out = (float*)d_out;

  char* ws = (char*)d_ws;
  size_t off = 0;
  auto alloc = [&](size_t b) { char* p = ws + off; off += (b + 255) & ~(size_t)255; return p; };
  unsigned short* Xb   = (unsigned short*)alloc((size_t)S_TOK * DIM  * 2);  // 16MB; later iqk|oqk (z=0)
  unsigned short* Yb   = (unsigned short*)alloc((size_t)S_TOK * DIM  * 2);  // 16MB; later iqk|oqk (z=1)
  unsigned short* Rb   = (unsigned short*)alloc((size_t)S_TOK * DIM  * 2);  // 16MB
  unsigned short* WiT  = (unsigned short*)alloc((size_t)DIM2 * DIM  * 2);   // 4MB
  unsigned short* WoT  = (unsigned short*)alloc((size_t)DIM2 * DIM  * 2);   // 4MB
  unsigned short* WcT  = (unsigned short*)alloc((size_t)DIM2 * DIM2 * 2);   // 8MB
  unsigned short* WfT  = (unsigned short*)alloc((size_t)OUTN * DIM2 * 2);   // 4MB
  unsigned short* iqT  = (unsigned short*)alloc((size_t)DIM2 * S_TOK * 2);  // 32MB; later meta0/1+MWT0/1
  unsigned short* oqT0 = (unsigned short*)alloc((size_t)DIM2 * S_TOK * 2);  // 32MB; later icm0
  unsigned short* oqT1 = (unsigned short*)alloc((size_t)DIM2 * S_TOK * 2);  // 32MB; later icm1
  unsigned short* icmT0= (unsigned short*)alloc((size_t)DIM2 * S_TOK * 2);  // 32MB
  unsigned short* icmT1= (unsigned short*)alloc((size_t)DIM2 * S_TOK * 2);  // 32MB
  // aliases (all write-before-read within each launch):
  unsigned short* iqk0 = Xb;                      // [2048,2048]
  unsigned short* oqk0 = Xb + (size_t)DIM2*DIM2;
  unsigned short* iqk1 = Yb;
  unsigned short* oqk1 = Yb + (size_t)DIM2*DIM2;
  unsigned short* meta0= iqT;                     // [2048,2048] each
  unsigned short* meta1= iqT + (size_t)DIM2*DIM2;
  unsigned short* MWT0 = iqT + (size_t)2*DIM2*DIM2;          // [1024,2048]
  unsigned short* MWT1 = iqT + (size_t)2*DIM2*DIM2 + (size_t)OUTN*DIM2;
  unsigned short* icm0 = oqT0;                    // [8192,2048]
  unsigned short* icm1 = oqT1;

  auto cvt = [&](const float* s, unsigned short* d, int n) {
    int n4 = n >> 2;
    cvt_f32_bf16<<<dim3((n4 + 255) / 256), dim3(256), 0, stream>>>(s, d, n4);
  };
  cvt(X, Xb, S_TOK * DIM);
  cvt(Y, Yb, S_TOK * DIM);
  cvt(R, Rb, S_TOK * DIM);
  transpose_to_bf16<1><<<dim3(DIM2 / 64, DIM  / 64), 256, 0, stream>>>(Wi, WiT, DIM,  DIM2);
  transpose_to_bf16<1><<<dim3(DIM2 / 64, DIM  / 64), 256, 0, stream>>>(Wo, WoT, DIM,  DIM2);
  transpose_to_bf16<1><<<dim3(DIM2 / 64, DIM2 / 64), 256, 0, stream>>>(Wc, WcT, DIM2, DIM2);
  transpose_to_bf16<1><<<dim3(OUTN / 64, DIM2 / 64), 256, 0, stream>>>(Wf, WfT, DIM2, OUTN);

  const float rscale = 0.022097086912079608f;  // 1/sqrt(2048)

  // G1: z=3 -> iqT = (X@Wi+bi)^T ; oqT0 = (Y@Wo+bo)^T ; oqT1 = (R@Wo+bo)^T
  {
    GPtr g{};
    g.A[0] = WiT; g.A[1] = WoT; g.A[2] = WoT;
    g.B[0] = Xb;  g.B[1] = Yb;  g.B[2] = Rb;
    g.bias[0] = bi; g.bias[1] = bo; g.bias[2] = bo;
    g.C[0] = iqT; g.C[1] = oqT0; g.C[2] = oqT1;
    gemm_nt<0,0,1,1><<<dim3(S_TOK/128, DIM2/128, 3), 256, 0, stream>>>(
        g, DIM, DIM, S_TOK, DIM, 1.f, 0);
  }
  // G2: z=2 -> icmT_z = (cat(X, Y|R)@Wc + bc)^T   (BSPLIT on the token features)
  {
    GPtr g{};
    g.A[0] = WcT; g.A[1] = WcT;
    g.B[0] = Xb;  g.B[1] = Xb;
    g.Bk2[0] = Yb; g.Bk2[1] = Rb;
    g.bias[0] = bc; g.bias[1] = bc;
    g.C[0] = icmT0; g.C[1] = icmT1;
    gemm_nt<0,1,1,1><<<dim3(S_TOK/128, DIM2/128, 2), 256, 0, stream>>>(
        g, DIM2, DIM, S_TOK, DIM2, 1.f, 0);
  }
  // SM: column-softmax all 5 activation maps in one dispatch
  {
    SmTab st{};
    st.T[0] = iqT; st.T[1] = oqT0; st.T[2] = oqT1; st.T[3] = icmT0; st.T[4] = icmT1;
    softmax_cols<<<dim3(S_TOK / 64, 5), dim3(512), 0, stream>>>(st);
  }
  // G3: z=2 -> [iqk_z; oqk_z] = [iqT; oqT_z] @ icmT_z^T   (M=4096, K=8192)
  {
    GPtr g{};
    g.A[0] = iqT; g.A[1] = iqT;
    g.Arow2[0] = oqT0; g.Arow2[1] = oqT1;
    g.B[0] = icmT0; g.B[1] = icmT1;
    g.C[0] = iqk0; g.C[1] = iqk1;
    gemm_nt<1,0,0,1><<<dim3(DIM2/128, 4096/128, 2), 256, 0, stream>>>(
        g, S_TOK, S_TOK, DIM2, S_TOK, 1.f, 0);
  }
  // T: icm_z = transpose(icmT_z)  (oqT_z storage is dead after G3)
  transpose_to_bf16<0><<<dim3(S_TOK / 64, DIM2 / 64), 256, 0, stream>>>(icmT0, icm0, DIM2, S_TOK);
  transpose_to_bf16<0><<<dim3(S_TOK / 64, DIM2 / 64), 256, 0, stream>>>(icmT1, icm1, DIM2, S_TOK);
  // G4: z=2 -> meta_z = relu(iqk_z @ oqk_z^T)
  {
    GPtr g{};
    g.A[0] = iqk0; g.A[1] = iqk1;
    g.B[0] = oqk0; g.B[1] = oqk1;
    g.C[0] = meta0; g.C[1] = meta1;
    gemm_nt<0,0,0,1><<<dim3(DIM2/128, DIM2/128, 2), 256, 0, stream>>>(
        g, DIM2, DIM2, DIM2, DIM2, 1.f, 1);
  }
  // G5: z=2 -> MWT_z = (WfT @ meta_z^T) * rscale  ( = (meta_z @ Wf)^T / sqrt(2048) )
  {
    GPtr g{};
    g.A[0] = WfT; g.A[1] = WfT;
    g.B[0] = meta0; g.B[1] = meta1;
    g.C[0] = MWT0; g.C[1] = MWT1;
    gemm_nt<0,0,0,1><<<dim3(DIM2/128, OUTN/128, 2), 256, 0, stream>>>(
        g, DIM2, DIM2, DIM2, DIM2, rscale, 0);
  }
  // G6: z=2 -> out_z = relu(icm_z @ MWT_z^T + bf)   [8192,1024] f32
  {
    GPtr g{};
    g.A[0] = icm0; g.A[1] = icm1;
    g.B[0] = MWT0; g.B[1] = MWT1;
    g.bias[0] = bf_; g.bias[1] = bf_;
    g.C[0] = out; g.C[1] = out + (size_t)S_TOK * OUTN;
    gemm_nt<0,0,0,0><<<dim3(OUTN/128, S_TOK/128, 2), 256, 0, stream>>>(
        g, DIM2, DIM2, OUTN, DIM2, 1.f, 1);
  }
  (void)in_sizes; (void)n_in; (void)out_size; (void)ws_size;
}

// Round 4
// 967.670 us; speedup vs baseline: 1.9500x; 1.0269x over previous
//
#include <hip/hip_runtime.h>

#define S_TOK 8192
#define DIM   1024
#define DIM2  2048
#define OUTN  1024

typedef __bf16 bf16x8 __attribute__((ext_vector_type(8)));
typedef float  f32x4  __attribute__((ext_vector_type(4)));
typedef short  s16x8  __attribute__((ext_vector_type(8)));
typedef unsigned short u16x4 __attribute__((ext_vector_type(4)));

__device__ __forceinline__ unsigned short f2bf(float x) {
  unsigned u = __builtin_bit_cast(unsigned, x);
  u = (u + 0x7FFFu + ((u >> 16) & 1u)) >> 16;
  return (unsigned short)u;
}
__device__ __forceinline__ float bf2f(unsigned short u) {
  return __builtin_bit_cast(float, (unsigned)u << 16);
}

__device__ __forceinline__ void gld_lds16(const void* g, void* l) {
  auto* g1 = reinterpret_cast<__attribute__((address_space(1))) unsigned*>(
      (unsigned long long)g);
  auto* l3 = reinterpret_cast<__attribute__((address_space(3))) unsigned*>(
      (unsigned long long)l);
  __builtin_amdgcn_global_load_lds(g1, l3, 16, 0, 0);
}

// Swizzled LDS byte offset for a [rows][64] bf16 tile (idx-major, k inner).
// XOR bits [6:4] with (idx ^ idx>>3)&7; staging keeps LDS linear and pre-XORs
// the GLOBAL source k-chunk instead (m173 pattern).
__device__ __forceinline__ int lds_off(int idx, int k) {
  int b = (idx << 7) + (k << 1);
  b ^= ((idx ^ (idx >> 3)) & 7) << 4;
  return b;
}

__global__ __launch_bounds__(256) void cvt_f32_bf16(const float* __restrict__ in,
                                                    unsigned short* __restrict__ out, int n4) {
  int i = blockIdx.x * 256 + threadIdx.x;
  if (i >= n4) return;
  float4 v = ((const float4*)in)[i];
  u16x4 o;
  o[0] = f2bf(v.x); o[1] = f2bf(v.y); o[2] = f2bf(v.z); o[3] = f2bf(v.w);
  *(u16x4*)(out + (size_t)i * 4) = o;
}

// Tiled transpose: in [R,C] (f32 or bf16) -> out [C,R] bf16. 64x64 tiles, 256 thr.
template <int F32IN>
__global__ __launch_bounds__(256) void transpose_to_bf16(const void* __restrict__ in,
                                                         unsigned short* __restrict__ out,
                                                         int R, int C) {
  __shared__ unsigned short t[64 * 64];
  const int r0 = blockIdx.y << 6, c0 = blockIdx.x << 6;
  const int tid = threadIdx.x;
#pragma unroll
  for (int i = 0; i < 2; ++i) {
    int ch = tid + (i << 8);
    int r = ch >> 3, c8 = (ch & 7) << 3;
    s16x8 w;
    if (F32IN) {
      const float* p = (const float*)in + (size_t)(r0 + r) * C + c0 + c8;
      float4 a = *(const float4*)p, b = *(const float4*)(p + 4);
      w[0] = (short)f2bf(a.x); w[1] = (short)f2bf(a.y);
      w[2] = (short)f2bf(a.z); w[3] = (short)f2bf(a.w);
      w[4] = (short)f2bf(b.x); w[5] = (short)f2bf(b.y);
      w[6] = (short)f2bf(b.z); w[7] = (short)f2bf(b.w);
    } else {
      w = *(const s16x8*)((const unsigned short*)in + (size_t)(r0 + r) * C + c0 + c8);
    }
    int sw = ((r ^ (r >> 3)) & 7) << 3;
    *(s16x8*)&t[(r << 6) + (c8 ^ sw)] = w;
  }
  __syncthreads();
#pragma unroll
  for (int i = 0; i < 2; ++i) {
    int ch = tid + (i << 8);
    int c = ch >> 3, r8 = (ch & 7) << 3;
    s16x8 w;
#pragma unroll
    for (int j = 0; j < 8; ++j) {
      int rr = r8 + j;
      w[j] = (short)t[(rr << 6) + (c ^ (((rr ^ (rr >> 3)) & 7) << 3))];
    }
    *(s16x8*)(out + (size_t)(c0 + c) * R + r0 + r8) = w;
  }
}

// Softmax over the ROW axis (2048 feats) of T [2048, S_TOK], per column, in place.
struct SmTab { unsigned short* T[6]; };
__global__ __launch_bounds__(512) void softmax_cols(SmTab tab) {
  unsigned short* T = tab.T[blockIdx.y];
  const int tid = threadIdx.x;
  const int colg = tid & 63, seg = tid >> 6;
  const size_t c = ((size_t)blockIdx.x << 6) + colg;
  float m = -1e30f, s = 0.f;
  for (int n = seg; n < DIM2; n += 8) {
    float v = bf2f(T[(size_t)n * S_TOK + c]);
    float mn = fmaxf(m, v);
    s = s * __expf(m - mn) + __expf(v - mn);
    m = mn;
  }
  __shared__ float redm[512], reds[512];
  redm[tid] = m; reds[tid] = s;
  __syncthreads();
  if (seg == 0) {
    float M = m, S = s;
#pragma unroll
    for (int k = 1; k < 8; ++k) {
      float mk = redm[colg + (k << 6)], sk = reds[colg + (k << 6)];
      float mn = fmaxf(M, mk);
      S = S * __expf(M - mn) + sk * __expf(mk - mn);
      M = mn;
    }
    redm[colg] = M; reds[colg] = 1.0f / S;
  }
  __syncthreads();
  m = redm[colg];
  const float inv = reds[colg];
  for (int n = seg; n < DIM2; n += 8) {
    size_t idx = (size_t)n * S_TOK + c;
    T[idx] = f2bf(__expf(bf2f(T[idx]) - m) * inv);
  }
}

struct GPtr {
  const unsigned short* A[3];
  const unsigned short* Arow2[3];
  const unsigned short* B[3];
  const unsigned short* Bk2[3];
  const float* bias[3];
  void* C[3];
};

// ---------------- 128x128 kernel (small GEMMs: G4, G5) ----------------
template <int ASPLIT, int BSPLIT, int BIAS_ROW, int OUT_BF16>
__global__ __launch_bounds__(256, 3) void gemm_nt(GPtr p, int lda, int ldb, int ldc,
                                                  int K, float scale, int do_relu) {
  __shared__ char lds[32768];
  char* As = lds;
  char* Bs = lds + 16384;
  const int z = blockIdx.z;
  const int tid  = threadIdx.x;
  const int lane = tid & 63;
  const int wave = tid >> 6;
  const int wm = (wave >> 1) << 6;
  const int wn = (wave & 1) << 6;
  const int m0 = blockIdx.y << 7;
  const int n0 = blockIdx.x << 7;

  const unsigned short* Au = p.A[z];
  int mb = m0;
  if (ASPLIT && m0 >= 2048) { Au = p.Arow2[z]; mb = m0 - 2048; }
  const unsigned short* B  = p.B[z];
  const unsigned short* B2 = BSPLIT ? p.Bk2[z] : B;
  const float* bias = p.bias[z];
  void* Cv = p.C[z];

  int srow[4], sgk[4];
#pragma unroll
  for (int i = 0; i < 4; ++i) {
    int c = (wave << 8) + (i << 6) + lane;
    int row = c >> 3, kc = c & 7;
    srow[i] = row;
    sgk[i]  = (kc ^ ((row ^ (row >> 3)) & 7)) << 3;
  }

  f32x4 acc[4][4];
#pragma unroll
  for (int i = 0; i < 4; ++i)
#pragma unroll
    for (int j = 0; j < 4; ++j) acc[i][j] = {0.f, 0.f, 0.f, 0.f};

  for (int k0 = 0; k0 < K; k0 += 64) {
    const unsigned short* bsrc = B;
    int kb = k0;
    if (BSPLIT && k0 >= DIM) { bsrc = B2; kb = k0 - DIM; }
#pragma unroll
    for (int i = 0; i < 4; ++i) {
      char* dA = As + (((wave << 2) + i) << 10);
      char* dB = Bs + (((wave << 2) + i) << 10);
      gld_lds16(Au   + (size_t)(mb + srow[i]) * lda + k0 + sgk[i], dA);
      gld_lds16(bsrc + (size_t)(n0 + srow[i]) * ldb + kb + sgk[i], dB);
    }
    __syncthreads();
#pragma unroll
    for (int ks = 0; ks < 2; ++ks) {
      bf16x8 af[4], bfr[4];
      int kk = (ks << 5) + ((lane >> 4) << 3);
#pragma unroll
      for (int t = 0; t < 4; ++t) {
        af[t]  = *(const bf16x8*)(As + lds_off(wm + (t << 4) + (lane & 15), kk));
        bfr[t] = *(const bf16x8*)(Bs + lds_off(wn + (t << 4) + (lane & 15), kk));
      }
#pragma unroll
      for (int mt = 0; mt < 4; ++mt)
#pragma unroll
        for (int nt = 0; nt < 4; ++nt)
          acc[mt][nt] = __builtin_amdgcn_mfma_f32_16x16x32_bf16(af[mt], bfr[nt], acc[mt][nt], 0, 0, 0);
    }
    __syncthreads();
  }

#pragma unroll
  for (int nt = 0; nt < 4; ++nt) {
    int col = n0 + wn + (nt << 4) + (lane & 15);
    float bcol = (!BIAS_ROW && bias) ? bias[col] : 0.0f;
#pragma unroll
    for (int mt = 0; mt < 4; ++mt) {
      f32x4 a = acc[mt][nt];
#pragma unroll
      for (int r = 0; r < 4; ++r) {
        int rowg = m0 + wm + (mt << 4) + ((lane >> 4) << 2) + r;
        float bv = BIAS_ROW ? (bias ? bias[rowg] : 0.0f) : bcol;
        float v = a[r] * scale + bv;
        if (do_relu) v = fmaxf(v, 0.0f);
        if (OUT_BF16) ((unsigned short*)Cv)[(size_t)rowg * ldc + col] = f2bf(v);
        else          ((float*)Cv)[(size_t)rowg * ldc + col] = v;
      }
    }
  }
}

// ---------------- 256x256 counted-vmcnt pipelined kernel ----------------
// BM=BN=256, BK=64, 512 thr = 8 waves (2M x 4N), per-wave 128x64 output.
// LDS 128KB: double-buffered A(32KB)+B(32KB). 2-deep prefetch, counted
// s_waitcnt vmcnt(8) across raw s_barrier (loads stay in flight), phase-split
// compute with setprio around MFMA clusters. Requires M,N % 256 == 0,
// K % 128 == 0, grid (x*y) % 8 == 0.
template <int ASPLIT, int BSPLIT, int BIAS_ROW, int OUT_BF16>
__global__ __launch_bounds__(512, 2) void gemm256(GPtr p, int lda, int ldb, int ldc,
                                                  int K, float scale, int do_relu) {
  __shared__ char lds[131072];
  const int z = blockIdx.z;
  const int tid  = threadIdx.x;
  const int lane = tid & 63;
  const int wave = tid >> 6;      // 0..7
  const int wm   = wave >> 2;     // 0..1  (M half)
  const int wn   = wave & 3;      // 0..3  (N quarter)

  // bijective XCD-chunked swizzle of the (x,y) block id (nwg % 8 == 0)
  const int gx = gridDim.x;
  const int nwg = gx * gridDim.y;
  int id = blockIdx.y * gx + blockIdx.x;
  id = (id & 7) * (nwg >> 3) + (id >> 3);
  const int n0 = (id % gx) << 8;
  const int m0 = (id / gx) << 8;

  const unsigned short* Au = p.A[z];
  int mb = m0;
  if (ASPLIT && m0 >= 2048) { Au = p.Arow2[z]; mb = m0 - 2048; }
  const unsigned short* Bp = p.B[z];
  const unsigned short* B2 = BSPLIT ? p.Bk2[z] : Bp;
  const float* bias = p.bias[z];
  void* Cv = p.C[z];

  // staging: A tile 256x64 = 2048 16B-chunks; chunk c = i*512 + tid.
  int srow[4], sgk[4];
#pragma unroll
  for (int i = 0; i < 4; ++i) {
    int c = (i << 9) + tid;
    int row = c >> 3, kc = c & 7;
    srow[i] = row;
    sgk[i]  = (kc ^ ((row ^ (row >> 3)) & 7)) << 3;  // pre-swizzled source k
  }

  // issues exactly 8 global_load_lds (4 A + 4 B) for K-tile t into buf[t&1]
  auto stage = [&](int t) {
    const int k0 = t << 6;
    char* Abase = lds + ((t & 1) << 16);
    char* Bbase = Abase + 32768;
    const unsigned short* bsrc = Bp;
    int kb = k0;
    if (BSPLIT && k0 >= DIM) { bsrc = B2; kb = k0 - DIM; }
#pragma unroll
    for (int i = 0; i < 4; ++i) {
      gld_lds16(Au   + (size_t)(mb + srow[i]) * lda + k0 + sgk[i],
                Abase + (i << 13) + (wave << 10));
      gld_lds16(bsrc + (size_t)(n0 + srow[i]) * ldb + kb + sgk[i],
                Bbase + (i << 13) + (wave << 10));
    }
  };

  f32x4 acc[8][4];
#pragma unroll
  for (int i = 0; i < 8; ++i)
#pragma unroll
    for (int j = 0; j < 4; ++j) acc[i][j] = {0.f, 0.f, 0.f, 0.f};

  const int NT = K >> 6;  // >= 2, even
  stage(0);
  stage(1);

  for (int t = 0; t < NT; ++t) {
    // wait for tile t's 8 loads; keep tile t+1's 8 in flight (counted vmcnt)
    if (t + 1 < NT) asm volatile("s_waitcnt vmcnt(8)" ::: "memory");
    else            asm volatile("s_waitcnt vmcnt(0)" ::: "memory");
    __builtin_amdgcn_s_barrier();
    __builtin_amdgcn_sched_barrier(0);
    const char* Ab = lds + ((t & 1) << 16);
    const char* Bb = Ab + 32768;
#pragma unroll
    for (int half = 0; half < 2; ++half) {
      const int kk = (half << 5) + ((lane >> 4) << 3);
      bf16x8 aq[4], bq[4];
      // phase A: B n0..3 + A m0..3, 16 MFMA
#pragma unroll
      for (int nf = 0; nf < 4; ++nf)
        bq[nf] = *(const bf16x8*)(Bb + lds_off((wn << 6) + (nf << 4) + (lane & 15), kk));
#pragma unroll
      for (int mf = 0; mf < 4; ++mf)
        aq[mf] = *(const bf16x8*)(Ab + lds_off((wm << 7) + (mf << 4) + (lane & 15), kk));
      __builtin_amdgcn_s_setprio(1);
#pragma unroll
      for (int mf = 0; mf < 4; ++mf)
#pragma unroll
        for (int nf = 0; nf < 4; ++nf)
          acc[mf][nf] = __builtin_amdgcn_mfma_f32_16x16x32_bf16(aq[mf], bq[nf], acc[mf][nf], 0, 0, 0);
      __builtin_amdgcn_s_setprio(0);
      __builtin_amdgcn_sched_barrier(0);
      // phase B: A m4..7, 16 MFMA (reuse bq)
#pragma unroll
      for (int mf = 0; mf < 4; ++mf)
        aq[mf] = *(const bf16x8*)(Ab + lds_off((wm << 7) + ((mf + 4) << 4) + (lane & 15), kk));
      __builtin_amdgcn_s_setprio(1);
#pragma unroll
      for (int mf = 0; mf < 4; ++mf)
#pragma unroll
        for (int nf = 0; nf < 4; ++nf)
          acc[mf + 4][nf] = __builtin_amdgcn_mfma_f32_16x16x32_bf16(aq[mf], bq[nf], acc[mf + 4][nf], 0, 0, 0);
      __builtin_amdgcn_s_setprio(0);
      __builtin_amdgcn_sched_barrier(0);
    }
    __builtin_amdgcn_s_barrier();   // all waves done reading buf[t&1]
    __builtin_amdgcn_sched_barrier(0);
    if (t + 2 < NT) stage(t + 2);   // refill the buffer just freed
  }

#pragma unroll
  for (int nf = 0; nf < 4; ++nf) {
    int col = n0 + (wn << 6) + (nf << 4) + (lane & 15);
    float bcol = (!BIAS_ROW && bias) ? bias[col] : 0.0f;
#pragma unroll
    for (int mf = 0; mf < 8; ++mf) {
      f32x4 a = acc[mf][nf];
#pragma unroll
      for (int r = 0; r < 4; ++r) {
        int rowg = m0 + (wm << 7) + (mf << 4) + ((lane >> 4) << 2) + r;
        float bv = BIAS_ROW ? (bias ? bias[rowg] : 0.0f) : bcol;
        float v = a[r] * scale + bv;
        if (do_relu) v = fmaxf(v, 0.0f);
        if (OUT_BF16) ((unsigned short*)Cv)[(size_t)rowg * ldc + col] = f2bf(v);
        else          ((float*)Cv)[(size_t)rowg * ldc + col] = v;
      }
    }
  }
}

extern "C" void kernel_launch(void* const* d_in, const int* in_sizes, int n_in,
                              void* d_out, int out_size, void* d_ws, size_t ws_size,
                              hipStream_t stream) {
  const float* X   = (const float*)d_in[0];
  const float* Y   = (const float*)d_in[1];
  const float* R   = (const float*)d_in[2];
  const float* Wi  = (const float*)d_in[3];
  const float* bi  = (const float*)d_in[4];
  const float* Wo  = (const float*)d_in[5];
  const float* bo  = (const float*)d_in[6];
  const float* Wc  = (const float*)d_in[7];
  const float* bc  = (const float*)d_in[8];
  const float* Wf  = (const float*)d_in[9];
  const float* bf_ = (const float*)d_in[10];
  float* out = (float*)d_out;

  char* ws = (char*)d_ws;
  size_t off = 0;
  auto alloc = [&](size_t b) { char* p = ws + off; off += (b + 255) & ~(size_t)255; return p; };
  unsigned short* Xb   = (unsigned short*)alloc((size_t)S_TOK * DIM  * 2);  // later iqk|oqk z=0
  unsigned short* Yb   = (unsigned short*)alloc((size_t)S_TOK * DIM  * 2);  // later iqk|oqk z=1
  unsigned short* Rb   = (unsigned short*)alloc((size_t)S_TOK * DIM  * 2);
  unsigned short* WiT  = (unsigned short*)alloc((size_t)DIM2 * DIM  * 2);
  unsigned short* WoT  = (unsigned short*)alloc((size_t)DIM2 * DIM  * 2);
  unsigned short* WcT  = (unsigned short*)alloc((size_t)DIM2 * DIM2 * 2);
  unsigned short* WfT  = (unsigned short*)alloc((size_t)OUTN * DIM2 * 2);
  unsigned short* iqT  = (unsigned short*)alloc((size_t)DIM2 * S_TOK * 2);  // later meta0/1+MWT0/1
  unsigned short* oqT0 = (unsigned short*)alloc((size_t)DIM2 * S_TOK * 2);  // later icm0
  unsigned short* oqT1 = (unsigned short*)alloc((size_t)DIM2 * S_TOK * 2);  // later icm1
  unsigned short* icmT0= (unsigned short*)alloc((size_t)DIM2 * S_TOK * 2);
  unsigned short* icmT1= (unsigned short*)alloc((size_t)DIM2 * S_TOK * 2);
  unsigned short* iqk0 = Xb;
  unsigned short* oqk0 = Xb + (size_t)DIM2*DIM2;
  unsigned short* iqk1 = Yb;
  unsigned short* oqk1 = Yb + (size_t)DIM2*DIM2;
  unsigned short* meta0= iqT;
  unsigned short* meta1= iqT + (size_t)DIM2*DIM2;
  unsigned short* MWT0 = iqT + (size_t)2*DIM2*DIM2;
  unsigned short* MWT1 = iqT + (size_t)2*DIM2*DIM2 + (size_t)OUTN*DIM2;
  unsigned short* icm0 = oqT0;
  unsigned short* icm1 = oqT1;

  auto cvt = [&](const float* s, unsigned short* d, int n) {
    int n4 = n >> 2;
    cvt_f32_bf16<<<dim3((n4 + 255) / 256), dim3(256), 0, stream>>>(s, d, n4);
  };
  cvt(X, Xb, S_TOK * DIM);
  cvt(Y, Yb, S_TOK * DIM);
  cvt(R, Rb, S_TOK * DIM);
  transpose_to_bf16<1><<<dim3(DIM2 / 64, DIM  / 64), 256, 0, stream>>>(Wi, WiT, DIM,  DIM2);
  transpose_to_bf16<1><<<dim3(DIM2 / 64, DIM  / 64), 256, 0, stream>>>(Wo, WoT, DIM,  DIM2);
  transpose_to_bf16<1><<<dim3(DIM2 / 64, DIM2 / 64), 256, 0, stream>>>(Wc, WcT, DIM2, DIM2);
  transpose_to_bf16<1><<<dim3(OUTN / 64, DIM2 / 64), 256, 0, stream>>>(Wf, WfT, DIM2, OUTN);

  const float rscale = 0.022097086912079608f;  // 1/sqrt(2048)

  // G1: z=3 -> iqT = (X@Wi+bi)^T ; oqT0 = (Y@Wo+bo)^T ; oqT1 = (R@Wo+bo)^T
  {
    GPtr g{};
    g.A[0] = WiT; g.A[1] = WoT; g.A[2] = WoT;
    g.B[0] = Xb;  g.B[1] = Yb;  g.B[2] = Rb;
    g.bias[0] = bi; g.bias[1] = bo; g.bias[2] = bo;
    g.C[0] = iqT; g.C[1] = oqT0; g.C[2] = oqT1;
    gemm256<0,0,1,1><<<dim3(S_TOK/256, DIM2/256, 3), 512, 0, stream>>>(
        g, DIM, DIM, S_TOK, DIM, 1.f, 0);
  }
  // G2: z=2 -> icmT_z = (cat(X, Y|R)@Wc + bc)^T
  {
    GPtr g{};
    g.A[0] = WcT; g.A[1] = WcT;
    g.B[0] = Xb;  g.B[1] = Xb;
    g.Bk2[0] = Yb; g.Bk2[1] = Rb;
    g.bias[0] = bc; g.bias[1] = bc;
    g.C[0] = icmT0; g.C[1] = icmT1;
    gemm256<0,1,1,1><<<dim3(S_TOK/256, DIM2/256, 2), 512, 0, stream>>>(
        g, DIM2, DIM, S_TOK, DIM2, 1.f, 0);
  }
  // SM: column-softmax all 5 activation maps
  {
    SmTab st{};
    st.T[0] = iqT; st.T[1] = oqT0; st.T[2] = oqT1; st.T[3] = icmT0; st.T[4] = icmT1;
    softmax_cols<<<dim3(S_TOK / 64, 5), dim3(512), 0, stream>>>(st);
  }
  // G3: z=2 -> [iqk_z; oqk_z] = [iqT; oqT_z] @ icmT_z^T   (M=4096, K=8192)
  {
    GPtr g{};
    g.A[0] = iqT; g.A[1] = iqT;
    g.Arow2[0] = oqT0; g.Arow2[1] = oqT1;
    g.B[0] = icmT0; g.B[1] = icmT1;
    g.C[0] = iqk0; g.C[1] = iqk1;
    gemm256<1,0,0,1><<<dim3(DIM2/256, 4096/256, 2), 512, 0, stream>>>(
        g, S_TOK, S_TOK, DIM2, S_TOK, 1.f, 0);
  }
  // T: icm_z = transpose(icmT_z)
  transpose_to_bf16<0><<<dim3(S_TOK / 64, DIM2 / 64), 256, 0, stream>>>(icmT0, icm0, DIM2, S_TOK);
  transpose_to_bf16<0><<<dim3(S_TOK / 64, DIM2 / 64), 256, 0, stream>>>(icmT1, icm1, DIM2, S_TOK);
  // G4: z=2 -> meta_z = relu(iqk_z @ oqk_z^T)   (128^2 kernel, 512 blocks)
  {
    GPtr g{};
    g.A[0] = iqk0; g.A[1] = iqk1;
    g.B[0] = oqk0; g.B[1] = oqk1;
    g.C[0] = meta0; g.C[1] = meta1;
    gemm_nt<0,0,0,1><<<dim3(DIM2/128, DIM2/128, 2), 256, 0, stream>>>(
        g, DIM2, DIM2, DIM2, DIM2, 1.f, 1);
  }
  // G5: z=2 -> MWT_z = (WfT @ meta_z^T) * rscale
  {
    GPtr g{};
    g.A[0] = WfT; g.A[1] = WfT;
    g.B[0] = meta0; g.B[1] = meta1;
    g.C[0] = MWT0; g.C[1] = MWT1;
    gemm_nt<0,0,0,1><<<dim3(DIM2/128, OUTN/128, 2), 256, 0, stream>>>(
        g, DIM2, DIM2, DIM2, DIM2, rscale, 0);
  }
  // G6: z=2 -> out_z = relu(icm_z @ MWT_z^T + bf)   [8192,1024] f32
  {
    GPtr g{};
    g.A[0] = icm0; g.A[1] = icm1;
    g.B[0] = MWT0; g.B[1] = MWT1;
    g.bias[0] = bf_; g.bias[1] = bf_;
    g.C[0] = out; g.C[1] = out + (size_t)S_TOK * OUTN;
    gemm256<0,0,0,0><<<dim3(OUTN/256, S_TOK/256, 2), 512, 0, stream>>>(
        g, DIM2, DIM2, OUTN, DIM2, 1.f, 1);
  }
  (void)in_sizes; (void)n_in; (void)out_size; (void)ws_size;
}